// Round 5
// baseline (373.773 us; speedup 1.0000x reference)
//
#include <hip/hip_runtime.h>
#include <hip/hip_bf16.h>
#include <cstdint>
#include <cstddef>

typedef _Float16 half8 __attribute__((ext_vector_type(8)));
typedef _Float16 half4 __attribute__((ext_vector_type(4)));
typedef float f32x4 __attribute__((ext_vector_type(4)));

#define NB 4
#define NL 1024
#define NHD 512
#define NH 8
#define ND 64
#define NBH 32

#define MFMA16(a, b, c) __builtin_amdgcn_mfma_f32_16x16x32_f16((a), (b), (c), 0, 0, 0)

// ---------------------------------------------------------------------------
// Mask width detection. flag=1: byte elements; flag=0: 4-byte elements.
// Batched uint4 loads (16 independent per lane -> one HBM latency epoch).
// ---------------------------------------------------------------------------
__global__ void detect_mask_kernel(const uint4* __restrict__ m, int* __restrict__ flag) {
    __shared__ int s_byte;
    if (threadIdx.x == 0) s_byte = 0;
    __syncthreads();
    uint4 v[4];
#pragma unroll
    for (int j = 0; j < 4; ++j) v[j] = m[threadIdx.x * 4 + j];
    int bad = 0;
#pragma unroll
    for (int j = 0; j < 4; ++j) {
        unsigned ws[4] = {v[j].x, v[j].y, v[j].z, v[j].w};
#pragma unroll
        for (int i = 0; i < 4; ++i)
            if (ws[i] != 0u && ws[i] != 1u && ws[i] != 0x3F800000u) bad = 1;
    }
    if (bad) atomicOr(&s_byte, 1);
    __syncthreads();
    if (threadIdx.x == 0) *flag = s_byte;
}

// ---------------------------------------------------------------------------
// Compress mask (32M elems) -> bitmask, 1 bit/elem, bit i of word t = elem 32t+i.
// ---------------------------------------------------------------------------
__global__ __launch_bounds__(256) void bitmask_kernel(
    const void* __restrict__ mask, const int* __restrict__ flagp, unsigned* __restrict__ mb)
{
    const int t = blockIdx.x * 256 + threadIdx.x;
    unsigned w = 0;
    if (*flagp == 1) {
        const uint4* p = (const uint4*)((const unsigned char*)mask + (size_t)t * 32);
        uint4 a = p[0], b = p[1];
        unsigned src[8] = {a.x, a.y, a.z, a.w, b.x, b.y, b.z, b.w};
#pragma unroll
        for (int j = 0; j < 8; ++j) {
            unsigned u = src[j];
            w |= ((u & 0x000000FFu) ? 1u : 0u) << (4 * j + 0);
            w |= ((u & 0x0000FF00u) ? 1u : 0u) << (4 * j + 1);
            w |= ((u & 0x00FF0000u) ? 1u : 0u) << (4 * j + 2);
            w |= ((u & 0xFF000000u) ? 1u : 0u) << (4 * j + 3);
        }
    } else {
        const uint4* p = (const uint4*)((const unsigned*)mask + (size_t)t * 32);
#pragma unroll
        for (int j = 0; j < 8; ++j) {
            uint4 v = p[j];
            w |= (v.x ? 1u : 0u) << (4 * j + 0);
            w |= (v.y ? 1u : 0u) << (4 * j + 1);
            w |= (v.z ? 1u : 0u) << (4 * j + 2);
            w |= (v.w ? 1u : 0u) << (4 * j + 3);
        }
    }
    mb[t] = w;
}

// ---------------------------------------------------------------------------
// QKV projection: out = X @ W_p^T + b_p  (M=4096, N=512, K=512), f16 MFMA.
// BM=128, BN=64, BK=64: 16 MFMA/wave-iter, 8 K-iters, 768 blocks (3/CU).
// proj 0 -> qb (pre-scaled 0.125), 1 -> kb, 2 -> vtb ([bh][d][l]).
// ---------------------------------------------------------------------------
__global__ __launch_bounds__(256) void qkv_gemm_kernel(
    const float* __restrict__ qin, const float* __restrict__ kin, const float* __restrict__ vin,
    const float* __restrict__ w, const float* __restrict__ bias,
    _Float16* __restrict__ qb, _Float16* __restrict__ kb, _Float16* __restrict__ vtb)
{
    const int mtile = blockIdx.x, ntile = blockIdx.y, proj = blockIdx.z;
    const float* A = proj == 0 ? qin : (proj == 1 ? kin : vin);
    const float* W = w + (size_t)proj * NHD * NHD;

    __shared__ __align__(16) _Float16 a_lds[128][72];
    __shared__ __align__(16) _Float16 b_lds[64][72];

    const int tid = threadIdx.x;
    const int wave = tid >> 6, lane = tid & 63, quad = lane >> 4, c = lane & 15;
    const int wm = wave >> 1, wn = wave & 1;

    f32x4 acc[4][2] = {};

    // staging map: A row = tid>>1 (128 rows), colseg = (tid&1)*32 (32 floats)
    //              B row = tid>>2 (64 rows),  colseg = (tid&3)*16 (16 floats)
    const int arow = tid >> 1, acol = (tid & 1) * 32;
    const int brow = tid >> 2, bcol = (tid & 3) * 16;
    const float* pa = &A[(size_t)(mtile * 128 + arow) * NHD + acol];
    const float* pb = &W[(size_t)(ntile * 64 + brow) * NHD + bcol];

    f32x4 ar[8], br[4];
#pragma unroll
    for (int j = 0; j < 8; ++j) ar[j] = *(const f32x4*)(pa + j * 4);
#pragma unroll
    for (int j = 0; j < 4; ++j) br[j] = *(const f32x4*)(pb + j * 4);

    for (int k0 = 0; k0 < NHD; k0 += 64) {
        half8 ah[4], bh_[2];
#pragma unroll
        for (int t = 0; t < 4; ++t)
#pragma unroll
            for (int j = 0; j < 4; ++j) {
                ah[t][j] = (_Float16)ar[2 * t][j];
                ah[t][4 + j] = (_Float16)ar[2 * t + 1][j];
            }
#pragma unroll
        for (int t = 0; t < 2; ++t)
#pragma unroll
            for (int j = 0; j < 4; ++j) {
                bh_[t][j] = (_Float16)br[2 * t][j];
                bh_[t][4 + j] = (_Float16)br[2 * t + 1][j];
            }
        __syncthreads();
#pragma unroll
        for (int t = 0; t < 4; ++t) *(half8*)&a_lds[arow][acol + t * 8] = ah[t];
#pragma unroll
        for (int t = 0; t < 2; ++t) *(half8*)&b_lds[brow][bcol + t * 8] = bh_[t];
        if (k0 < NHD - 64) {
            const float* na = pa + k0 + 64;
            const float* nb = pb + k0 + 64;
#pragma unroll
            for (int j = 0; j < 8; ++j) ar[j] = *(const f32x4*)(na + j * 4);
#pragma unroll
            for (int j = 0; j < 4; ++j) br[j] = *(const f32x4*)(nb + j * 4);
        }
        __syncthreads();

#pragma unroll
        for (int kk = 0; kk < 2; ++kk) {
            half8 af[4], bf[2];
#pragma unroll
            for (int ms = 0; ms < 4; ++ms)
                af[ms] = *(const half8*)&a_lds[wm * 64 + ms * 16 + c][kk * 32 + quad * 8];
#pragma unroll
            for (int ns = 0; ns < 2; ++ns)
                bf[ns] = *(const half8*)&b_lds[wn * 32 + ns * 16 + c][kk * 32 + quad * 8];
#pragma unroll
            for (int ms = 0; ms < 4; ++ms)
#pragma unroll
                for (int ns = 0; ns < 2; ++ns)
                    acc[ms][ns] = MFMA16(af[ms], bf[ns], acc[ms][ns]);
        }
    }

#pragma unroll
    for (int ms = 0; ms < 4; ++ms)
#pragma unroll
    for (int ns = 0; ns < 2; ++ns) {
        const int Cc = ntile * 64 + wn * 32 + ns * 16 + c;
        const float bv = bias[proj * NHD + Cc];
        const int h = Cc >> 6, d = Cc & 63;
#pragma unroll
        for (int r = 0; r < 4; ++r) {
            const int R = mtile * 128 + wm * 64 + ms * 16 + quad * 4 + r;
            const int b = R >> 10, l = R & 1023;
            const int bh = b * NH + h;
            float val = acc[ms][ns][r] + bv;
            if (proj == 0) {
                qb[((size_t)(bh * NL + l)) * ND + d] = (_Float16)(val * 0.125f);
            } else if (proj == 1) {
                kb[((size_t)(bh * NL + l)) * ND + d] = (_Float16)val;
            } else {
                vtb[((size_t)(bh * ND + d)) * NL + l] = (_Float16)val;
            }
        }
    }
}

// ---------------------------------------------------------------------------
// Flash attention, SPLIT-K x4: block (qt, bh, seg) processes 4 of 16 k-tiles,
// writes unnormalized O partial + per-row (m, l). Exact under online softmax.
// ---------------------------------------------------------------------------
__global__ __launch_bounds__(256) void attn_kernel(
    const _Float16* __restrict__ qb, const _Float16* __restrict__ kb, const _Float16* __restrict__ vtb,
    const float* __restrict__ kern, const unsigned* __restrict__ mb,
    float* __restrict__ pO, float* __restrict__ pm, float* __restrict__ pl)
{
    const int qt = blockIdx.x, bh = blockIdx.y, seg = blockIdx.z;
    const int tid = threadIdx.x, wave = tid >> 6, lane = tid & 63, quad = lane >> 4, c = lane & 15;
    const int q_base = qt * 64 + wave * 16;
    const int kt0 = seg * 4;

    __shared__ __align__(16) _Float16 k_lds[64][72];
    __shared__ __align__(16) _Float16 vt_lds[64][72];
    __shared__ __align__(16) _Float16 p_lds[64][72];
    __shared__ __align__(16) float bias_lds[64][68];   // [k][q]
    __shared__ unsigned mask_lds[64][2];               // [q][k-word]

    half8 aq0 = *(const half8*)&qb[((size_t)(bh * NL) + q_base + c) * ND + quad * 8];
    half8 aq1 = *(const half8*)&qb[((size_t)(bh * NL) + q_base + c) * ND + 32 + quad * 8];

    f32x4 O[4] = {};
    float m_i[4] = {-1e30f, -1e30f, -1e30f, -1e30f};
    float l_i[4] = {0.f, 0.f, 0.f, 0.f};

    const int sr = tid >> 2, sc = (tid & 3) * 16;

    half8 kr0, kr1, vr0, vr1;
    f32x4 gr[4];
    unsigned mr = 0;

    // prologue loads for global tile kt0
    {
        const _Float16* pk = &kb[((size_t)(bh * NL) + kt0 * 64 + sr) * ND + sc];
        kr0 = *(const half8*)pk; kr1 = *(const half8*)(pk + 8);
        const _Float16* pv = &vtb[((size_t)(bh * ND) + sr) * NL + kt0 * 64 + sc];
        vr0 = *(const half8*)pv; vr1 = *(const half8*)(pv + 8);
        const float* pg = &kern[((size_t)bh * NL + kt0 * 64 + sr) * NL + qt * 64 + sc];
#pragma unroll
        for (int j = 0; j < 4; ++j) gr[j] = *(const f32x4*)(pg + j * 4);
        if (tid < 128) mr = mb[((size_t)bh * NL + qt * 64 + (tid >> 1)) * 32 + kt0 * 2 + (tid & 1)];
    }

    for (int kt = 0; kt < 4; ++kt) {
        __syncthreads();
        *(half8*)&k_lds[sr][sc] = kr0;  *(half8*)&k_lds[sr][sc + 8] = kr1;
        *(half8*)&vt_lds[sr][sc] = vr0; *(half8*)&vt_lds[sr][sc + 8] = vr1;
#pragma unroll
        for (int j = 0; j < 4; ++j) *(f32x4*)&bias_lds[sr][(tid & 3) * 16 + j * 4] = gr[j];
        if (tid < 128) mask_lds[tid >> 1][tid & 1] = mr;

        if (kt < 3) {
            const int ktg = kt0 + kt + 1;
            const _Float16* pk = &kb[((size_t)(bh * NL) + ktg * 64 + sr) * ND + sc];
            kr0 = *(const half8*)pk; kr1 = *(const half8*)(pk + 8);
            const _Float16* pv = &vtb[((size_t)(bh * ND) + sr) * NL + ktg * 64 + sc];
            vr0 = *(const half8*)pv; vr1 = *(const half8*)(pv + 8);
            const float* pg = &kern[((size_t)bh * NL + ktg * 64 + sr) * NL + qt * 64 + sc];
#pragma unroll
            for (int j = 0; j < 4; ++j) gr[j] = *(const f32x4*)(pg + j * 4);
            if (tid < 128) mr = mb[((size_t)bh * NL + qt * 64 + (tid >> 1)) * 32 + ktg * 2 + (tid & 1)];
        }
        __syncthreads();

        // S = (q*scale) @ k^T
        f32x4 S[4];
#pragma unroll
        for (int ns = 0; ns < 4; ++ns) {
            f32x4 a = {};
            half8 bk0 = *(const half8*)&k_lds[ns * 16 + c][quad * 8];
            half8 bk1 = *(const half8*)&k_lds[ns * 16 + c][32 + quad * 8];
            a = MFMA16(aq0, bk0, a);
            a = MFMA16(aq1, bk1, a);
            S[ns] = a;
        }

        unsigned mw0[4], mw1[4];
#pragma unroll
        for (int r = 0; r < 4; ++r) {
            const int row = wave * 16 + quad * 4 + r;
            uint2 mm = *(const uint2*)&mask_lds[row][0];
            mw0[r] = mm.x; mw1[r] = mm.y;
        }

        // + kernel^T (bias_lds is [k-in-tile][q-in-64tile]; wave offset REQUIRED)
#pragma unroll
        for (int ns = 0; ns < 4; ++ns) {
            f32x4 bv = *(const f32x4*)&bias_lds[ns * 16 + c][wave * 16 + quad * 4];
            const int bit = ((ns & 1) << 4) + c;
#pragma unroll
            for (int r = 0; r < 4; ++r) {
                unsigned w = (ns < 2) ? mw0[r] : mw1[r];
                bool mk = (w >> bit) & 1u;
                S[ns][r] = mk ? -1e30f : (S[ns][r] + bv[r]);
            }
        }

        // online softmax across this tile's 64 k-cols
        float pmax[4], al[4];
#pragma unroll
        for (int r = 0; r < 4; ++r) {
            float t = fmaxf(fmaxf(S[0][r], S[1][r]), fmaxf(S[2][r], S[3][r]));
            t = fmaxf(t, __shfl_xor(t, 1));
            t = fmaxf(t, __shfl_xor(t, 2));
            t = fmaxf(t, __shfl_xor(t, 4));
            t = fmaxf(t, __shfl_xor(t, 8));
            float mn = fmaxf(m_i[r], t);
            al[r] = __expf(m_i[r] - mn);
            m_i[r] = mn;
            pmax[r] = mn;
        }
        float rs[4] = {0.f, 0.f, 0.f, 0.f};
#pragma unroll
        for (int ns = 0; ns < 4; ++ns)
#pragma unroll
            for (int r = 0; r < 4; ++r) {
                float p = __expf(S[ns][r] - pmax[r]);
                S[ns][r] = p;
                rs[r] += p;
            }
#pragma unroll
        for (int r = 0; r < 4; ++r) {
            float t = rs[r];
            t += __shfl_xor(t, 1);
            t += __shfl_xor(t, 2);
            t += __shfl_xor(t, 4);
            t += __shfl_xor(t, 8);
            l_i[r] = l_i[r] * al[r] + t;
        }
#pragma unroll
        for (int ds = 0; ds < 4; ++ds)
#pragma unroll
            for (int r = 0; r < 4; ++r)
                O[ds][r] *= al[r];

        // P (C-layout) -> LDS -> A-layout; wave-local rows, lgkmcnt suffices.
#pragma unroll
        for (int ns = 0; ns < 4; ++ns)
#pragma unroll
            for (int r = 0; r < 4; ++r)
                p_lds[wave * 16 + quad * 4 + r][ns * 16 + c] = (_Float16)S[ns][r];
        __asm__ volatile("s_waitcnt lgkmcnt(0)" ::: "memory");

#pragma unroll
        for (int ks = 0; ks < 2; ++ks) {
            half8 ap = *(const half8*)&p_lds[wave * 16 + c][ks * 32 + quad * 8];
#pragma unroll
            for (int ds = 0; ds < 4; ++ds) {
                half8 bv = *(const half8*)&vt_lds[ds * 16 + c][ks * 32 + quad * 8];
                O[ds] = MFMA16(ap, bv, O[ds]);
            }
        }
    }

    const int ub = (bh * 16 + qt) * 4 + seg;
    float* pOb = pO + (size_t)ub * 4096;
#pragma unroll
    for (int ds = 0; ds < 4; ++ds)
#pragma unroll
        for (int r = 0; r < 4; ++r)
            pOb[(wave * 16 + quad * 4 + r) * 64 + ds * 16 + c] = O[ds][r];
    if (c == 0) {
#pragma unroll
        for (int r = 0; r < 4; ++r) {
            const int row = wave * 16 + quad * 4 + r;
            pm[(size_t)ub * 64 + row] = m_i[r];
            pl[(size_t)ub * 64 + row] = l_i[r];
        }
    }
}

// ---------------------------------------------------------------------------
// Split-K merge (4-way): combine, normalize, write ctx f16 (merged heads).
// ---------------------------------------------------------------------------
__global__ __launch_bounds__(256) void merge_kernel(
    const float* __restrict__ pO, const float* __restrict__ pm, const float* __restrict__ pl,
    _Float16* __restrict__ ctx)
{
    const int qt = blockIdx.x, bh = blockIdx.y;
    const int u0 = (bh * 16 + qt) * 4;
    __shared__ float sc_[4][64];
    const int tid = threadIdx.x;
    if (tid < 64) {
        float mm[4], ll[4];
        float m = -1e30f;
#pragma unroll
        for (int j = 0; j < 4; ++j) {
            mm[j] = pm[(size_t)(u0 + j) * 64 + tid];
            ll[j] = pl[(size_t)(u0 + j) * 64 + tid];
            m = fmaxf(m, mm[j]);
        }
        float l = 0.f, e[4];
#pragma unroll
        for (int j = 0; j < 4; ++j) { e[j] = __expf(mm[j] - m); l += ll[j] * e[j]; }
        float linv = 1.0f / l;
#pragma unroll
        for (int j = 0; j < 4; ++j) sc_[j][tid] = e[j] * linv;
    }
    __syncthreads();
    const int b = bh >> 3, h = bh & 7;
#pragma unroll
    for (int js = 0; js < 4; ++js) {
        const int idx = js * 1024 + tid * 4;
        const int row = idx >> 6, col = idx & 63;
        f32x4 s = {};
#pragma unroll
        for (int j = 0; j < 4; ++j) {
            f32x4 a = *(const f32x4*)(pO + (size_t)(u0 + j) * 4096 + idx);
            const float w = sc_[j][row];
#pragma unroll
            for (int i = 0; i < 4; ++i) s[i] += a[i] * w;
        }
        half4 o;
#pragma unroll
        for (int i = 0; i < 4; ++i) o[i] = (_Float16)s[i];
        *(half4*)&ctx[((size_t)(b * NL + qt * 64 + row)) * NHD + h * ND + col] = o;
    }
}

// ---------------------------------------------------------------------------
// Output projection: out = ctx @ out_w^T + out_b, f32 output. BK=64 pipeline.
// ---------------------------------------------------------------------------
__global__ __launch_bounds__(256) void out_gemm_kernel(
    const _Float16* __restrict__ ctx, const float* __restrict__ w, const float* __restrict__ bias,
    float* __restrict__ out)
{
    const int mtile = blockIdx.x, ntile = blockIdx.y;
    __shared__ __align__(16) _Float16 a_lds[64][72];
    __shared__ __align__(16) _Float16 b_lds[64][72];
    const int tid = threadIdx.x, wave = tid >> 6, lane = tid & 63, quad = lane >> 4, c = lane & 15;
    const int wm = wave >> 1, wn = wave & 1;
    f32x4 acc[2][2] = {};

    const int sr = tid >> 2, sc = (tid & 3) * 16;
    const _Float16* pa = &ctx[(size_t)(mtile * 64 + sr) * NHD + sc];
    const float* pb = &w[(size_t)(ntile * 64 + sr) * NHD + sc];

    half8 ah0, ah1;
    f32x4 br[4];
    ah0 = *(const half8*)pa; ah1 = *(const half8*)(pa + 8);
#pragma unroll
    for (int j = 0; j < 4; ++j) br[j] = *(const f32x4*)(pb + j * 4);

    for (int k0 = 0; k0 < NHD; k0 += 64) {
        half8 bh0, bh1;
#pragma unroll
        for (int j = 0; j < 4; ++j) {
            bh0[j] = (_Float16)br[0][j]; bh0[4 + j] = (_Float16)br[1][j];
            bh1[j] = (_Float16)br[2][j]; bh1[4 + j] = (_Float16)br[3][j];
        }
        __syncthreads();
        *(half8*)&a_lds[sr][sc] = ah0; *(half8*)&a_lds[sr][sc + 8] = ah1;
        *(half8*)&b_lds[sr][sc] = bh0; *(half8*)&b_lds[sr][sc + 8] = bh1;
        if (k0 < NHD - 64) {
            const _Float16* na = pa + k0 + 64;
            const float* nb = pb + k0 + 64;
            ah0 = *(const half8*)na; ah1 = *(const half8*)(na + 8);
#pragma unroll
            for (int j = 0; j < 4; ++j) br[j] = *(const f32x4*)(nb + j * 4);
        }
        __syncthreads();

#pragma unroll
        for (int kk = 0; kk < 2; ++kk) {
            half8 af0 = *(const half8*)&a_lds[wm * 32 + c][kk * 32 + quad * 8];
            half8 af1 = *(const half8*)&a_lds[wm * 32 + 16 + c][kk * 32 + quad * 8];
            half8 bf0 = *(const half8*)&b_lds[wn * 32 + c][kk * 32 + quad * 8];
            half8 bf1 = *(const half8*)&b_lds[wn * 32 + 16 + c][kk * 32 + quad * 8];
            acc[0][0] = MFMA16(af0, bf0, acc[0][0]);
            acc[0][1] = MFMA16(af0, bf1, acc[0][1]);
            acc[1][0] = MFMA16(af1, bf0, acc[1][0]);
            acc[1][1] = MFMA16(af1, bf1, acc[1][1]);
        }
    }

#pragma unroll
    for (int ms = 0; ms < 2; ++ms)
#pragma unroll
    for (int ns = 0; ns < 2; ++ns) {
        const int Cc = ntile * 64 + wn * 32 + ns * 16 + c;
        const float bv = bias[Cc];
#pragma unroll
        for (int r = 0; r < 4; ++r) {
            const int R = mtile * 64 + wm * 32 + ms * 16 + quad * 4 + r;
            out[(size_t)R * NHD + Cc] = acc[ms][ns][r] + bv;
        }
    }
}

extern "C" void kernel_launch(void* const* d_in, const int* in_sizes, int n_in,
                              void* d_out, int out_size, void* d_ws, size_t ws_size,
                              hipStream_t stream)
{
    const float* query = (const float*)d_in[0];
    const float* key_  = (const float*)d_in[1];
    const float* value = (const float*)d_in[2];
    const void*  mask  = d_in[3];
    const float* kern  = (const float*)d_in[5];
    const float* ipw   = (const float*)d_in[6];
    const float* ipb   = (const float*)d_in[7];
    const float* outw  = (const float*)d_in[8];
    const float* outb  = (const float*)d_in[9];

    char* ws = (char*)d_ws;
    _Float16* qb  = (_Float16*)(ws);                    // 4 MB  [BH][L][D]
    _Float16* kb  = (_Float16*)(ws + (4ull << 20));     // 4 MB  [BH][L][D]
    _Float16* vtb = (_Float16*)(ws + (8ull << 20));     // 4 MB  [BH][D][L]
    _Float16* ctx = (_Float16*)(ws + (12ull << 20));    // 4 MB  [B][L][HD]
    int* flag     = (int*)(ws + (16ull << 20));         // 4 B
    float* pO     = (float*)(ws + (24ull << 20));       // 32 MB [2048][64][64]
    float* pm     = (float*)(ws + (56ull << 20));       // 512 KB
    float* pl     = (float*)(ws + (57ull << 20));       // 512 KB

    // Bitmask scratch in d_out (8 MB f32; mb needs 4 MB; fully overwritten later).
    unsigned* mb = (unsigned*)d_out;

    detect_mask_kernel<<<1, 256, 0, stream>>>((const uint4*)mask, flag);
    bitmask_kernel<<<4096, 256, 0, stream>>>(mask, flag, mb);
    qkv_gemm_kernel<<<dim3(32, 8, 3), 256, 0, stream>>>(query, key_, value, ipw, ipb, qb, kb, vtb);
    attn_kernel<<<dim3(16, 32, 4), 256, 0, stream>>>(qb, kb, vtb, kern, mb, pO, pm, pl);
    merge_kernel<<<dim3(16, 32), 256, 0, stream>>>(pO, pm, pl, ctx);
    out_gemm_kernel<<<dim3(64, 8), 256, 0, stream>>>(ctx, outw, outb, (float*)d_out);
}

// Round 6
// 368.127 us; speedup vs baseline: 1.0153x; 1.0153x over previous
//
#include <hip/hip_runtime.h>
#include <hip/hip_bf16.h>
#include <cstdint>
#include <cstddef>

typedef _Float16 half8 __attribute__((ext_vector_type(8)));
typedef _Float16 half4 __attribute__((ext_vector_type(4)));
typedef float f32x4 __attribute__((ext_vector_type(4)));

#define NB 4
#define NL 1024
#define NHD 512
#define NH 8
#define ND 64
#define NBH 32

#define MFMA16(a, b, c) __builtin_amdgcn_mfma_f32_16x16x32_f16((a), (b), (c), 0, 0, 0)

// ---------------------------------------------------------------------------
// Bitmask with per-block self-detection. Each block reads 2048 words; byte
// masks (0x00/0x01 bytes) produce a word outside {0,1,0x3F800000} w.p.
// 1-0.857^2048 ~ 1, so detection is per-block certain. int32/f32 masks never
// trip it (words are exactly 0/1/0x3F800000). Fast (byte) path re-uses the
// already-loaded registers: zero extra traffic.
// Output: 1 bit/elem, bit i of word t = elem 32t+i.
// ---------------------------------------------------------------------------
__global__ __launch_bounds__(256) void bitmask_kernel(
    const void* __restrict__ mask, unsigned* __restrict__ mb)
{
    __shared__ int s_byte;
    const int tid = threadIdx.x;
    const int t = blockIdx.x * 256 + tid;
    if (tid == 0) s_byte = 0;
    __syncthreads();

    const uint4* p = (const uint4*)((const unsigned char*)mask + (size_t)t * 32);
    uint4 a = p[0], b = p[1];
    unsigned src[8] = {a.x, a.y, a.z, a.w, b.x, b.y, b.z, b.w};
    int bad = 0;
#pragma unroll
    for (int j = 0; j < 8; ++j)
        if (src[j] != 0u && src[j] != 1u && src[j] != 0x3F800000u) bad = 1;
    if (bad) atomicOr(&s_byte, 1);
    __syncthreads();

    unsigned w = 0;
    if (s_byte) {
        // byte elements: the 32 bytes already in src are this thread's 32 elems
#pragma unroll
        for (int j = 0; j < 8; ++j) {
            unsigned u = src[j];
            w |= ((u & 0x000000FFu) ? 1u : 0u) << (4 * j + 0);
            w |= ((u & 0x0000FF00u) ? 1u : 0u) << (4 * j + 1);
            w |= ((u & 0x00FF0000u) ? 1u : 0u) << (4 * j + 2);
            w |= ((u & 0xFF000000u) ? 1u : 0u) << (4 * j + 3);
        }
    } else {
        // 4-byte elements (int32 {0,1} or f32 {0,1.0f}): re-read 32 words
        const uint4* q = (const uint4*)((const unsigned*)mask + (size_t)t * 32);
#pragma unroll
        for (int j = 0; j < 8; ++j) {
            uint4 v = q[j];
            w |= (v.x ? 1u : 0u) << (4 * j + 0);
            w |= (v.y ? 1u : 0u) << (4 * j + 1);
            w |= (v.z ? 1u : 0u) << (4 * j + 2);
            w |= (v.w ? 1u : 0u) << (4 * j + 3);
        }
    }
    mb[t] = w;
}

// ---------------------------------------------------------------------------
// QKV projection: out = X @ W_p^T + b_p  (M=4096, N=512, K=512), f16 MFMA.
// BM=128, BN=64, BK=64. proj 0 -> qb (pre-scaled 0.125), 1 -> kb,
// 2 -> vtb (transposed [bh][d][l]).
// ---------------------------------------------------------------------------
__global__ __launch_bounds__(256) void qkv_gemm_kernel(
    const float* __restrict__ qin, const float* __restrict__ kin, const float* __restrict__ vin,
    const float* __restrict__ w, const float* __restrict__ bias,
    _Float16* __restrict__ qb, _Float16* __restrict__ kb, _Float16* __restrict__ vtb)
{
    const int mtile = blockIdx.x, ntile = blockIdx.y, proj = blockIdx.z;
    const float* A = proj == 0 ? qin : (proj == 1 ? kin : vin);
    const float* W = w + (size_t)proj * NHD * NHD;

    __shared__ __align__(16) _Float16 a_lds[128][72];
    __shared__ __align__(16) _Float16 b_lds[64][72];

    const int tid = threadIdx.x;
    const int wave = tid >> 6, lane = tid & 63, quad = lane >> 4, c = lane & 15;
    const int wm = wave >> 1, wn = wave & 1;

    f32x4 acc[4][2] = {};

    const int arow = tid >> 1, acol = (tid & 1) * 32;
    const int brow = tid >> 2, bcol = (tid & 3) * 16;
    const float* pa = &A[(size_t)(mtile * 128 + arow) * NHD + acol];
    const float* pb = &W[(size_t)(ntile * 64 + brow) * NHD + bcol];

    f32x4 ar[8], br[4];
#pragma unroll
    for (int j = 0; j < 8; ++j) ar[j] = *(const f32x4*)(pa + j * 4);
#pragma unroll
    for (int j = 0; j < 4; ++j) br[j] = *(const f32x4*)(pb + j * 4);

    for (int k0 = 0; k0 < NHD; k0 += 64) {
        half8 ah[4], bh_[2];
#pragma unroll
        for (int t = 0; t < 4; ++t)
#pragma unroll
            for (int j = 0; j < 4; ++j) {
                ah[t][j] = (_Float16)ar[2 * t][j];
                ah[t][4 + j] = (_Float16)ar[2 * t + 1][j];
            }
#pragma unroll
        for (int t = 0; t < 2; ++t)
#pragma unroll
            for (int j = 0; j < 4; ++j) {
                bh_[t][j] = (_Float16)br[2 * t][j];
                bh_[t][4 + j] = (_Float16)br[2 * t + 1][j];
            }
        __syncthreads();
#pragma unroll
        for (int t = 0; t < 4; ++t) *(half8*)&a_lds[arow][acol + t * 8] = ah[t];
#pragma unroll
        for (int t = 0; t < 2; ++t) *(half8*)&b_lds[brow][bcol + t * 8] = bh_[t];
        if (k0 < NHD - 64) {
            const float* na = pa + k0 + 64;
            const float* nb = pb + k0 + 64;
#pragma unroll
            for (int j = 0; j < 8; ++j) ar[j] = *(const f32x4*)(na + j * 4);
#pragma unroll
            for (int j = 0; j < 4; ++j) br[j] = *(const f32x4*)(nb + j * 4);
        }
        __syncthreads();

#pragma unroll
        for (int kk = 0; kk < 2; ++kk) {
            half8 af[4], bf[2];
#pragma unroll
            for (int ms = 0; ms < 4; ++ms)
                af[ms] = *(const half8*)&a_lds[wm * 64 + ms * 16 + c][kk * 32 + quad * 8];
#pragma unroll
            for (int ns = 0; ns < 2; ++ns)
                bf[ns] = *(const half8*)&b_lds[wn * 32 + ns * 16 + c][kk * 32 + quad * 8];
#pragma unroll
            for (int ms = 0; ms < 4; ++ms)
#pragma unroll
                for (int ns = 0; ns < 2; ++ns)
                    acc[ms][ns] = MFMA16(af[ms], bf[ns], acc[ms][ns]);
        }
    }

#pragma unroll
    for (int ms = 0; ms < 4; ++ms)
#pragma unroll
    for (int ns = 0; ns < 2; ++ns) {
        const int Cc = ntile * 64 + wn * 32 + ns * 16 + c;
        const float bv = bias[proj * NHD + Cc];
        const int h = Cc >> 6, d = Cc & 63;
#pragma unroll
        for (int r = 0; r < 4; ++r) {
            const int R = mtile * 128 + wm * 64 + ms * 16 + quad * 4 + r;
            const int b = R >> 10, l = R & 1023;
            const int bh = b * NH + h;
            float val = acc[ms][ns][r] + bv;
            if (proj == 0) {
                qb[((size_t)(bh * NL + l)) * ND + d] = (_Float16)(val * 0.125f);
            } else if (proj == 1) {
                kb[((size_t)(bh * NL + l)) * ND + d] = (_Float16)val;
            } else {
                vtb[((size_t)(bh * ND + d)) * NL + l] = (_Float16)val;
            }
        }
    }
}

// ---------------------------------------------------------------------------
// Flash attention, SPLIT-K x2: block (qt, bh, half) processes 8 of 16 k-tiles,
// writes unnormalized O partial (f16) + per-row (m, l) f32.
// ---------------------------------------------------------------------------
__global__ __launch_bounds__(256) void attn_kernel(
    const _Float16* __restrict__ qb, const _Float16* __restrict__ kb, const _Float16* __restrict__ vtb,
    const float* __restrict__ kern, const unsigned* __restrict__ mb,
    _Float16* __restrict__ pO, float* __restrict__ pm, float* __restrict__ pl)
{
    const int qt = blockIdx.x, bh = blockIdx.y, half = blockIdx.z;
    const int tid = threadIdx.x, wave = tid >> 6, lane = tid & 63, quad = lane >> 4, c = lane & 15;
    const int q_base = qt * 64 + wave * 16;
    const int kt0 = half * 8;

    __shared__ __align__(16) _Float16 k_lds[64][72];
    __shared__ __align__(16) _Float16 vt_lds[64][72];
    __shared__ __align__(16) _Float16 p_lds[64][72];
    __shared__ __align__(16) float bias_lds[64][68];   // [k][q]
    __shared__ unsigned mask_lds[64][2];               // [q][k-word]

    half8 aq0 = *(const half8*)&qb[((size_t)(bh * NL) + q_base + c) * ND + quad * 8];
    half8 aq1 = *(const half8*)&qb[((size_t)(bh * NL) + q_base + c) * ND + 32 + quad * 8];

    f32x4 O[4] = {};
    float m_i[4] = {-1e30f, -1e30f, -1e30f, -1e30f};
    float l_i[4] = {0.f, 0.f, 0.f, 0.f};

    const int sr = tid >> 2, sc = (tid & 3) * 16;

    half8 kr0, kr1, vr0, vr1;
    f32x4 gr[4];
    unsigned mr = 0;

    // prologue loads for global tile kt0
    {
        const _Float16* pk = &kb[((size_t)(bh * NL) + kt0 * 64 + sr) * ND + sc];
        kr0 = *(const half8*)pk; kr1 = *(const half8*)(pk + 8);
        const _Float16* pv = &vtb[((size_t)(bh * ND) + sr) * NL + kt0 * 64 + sc];
        vr0 = *(const half8*)pv; vr1 = *(const half8*)(pv + 8);
        const float* pg = &kern[((size_t)bh * NL + kt0 * 64 + sr) * NL + qt * 64 + sc];
#pragma unroll
        for (int j = 0; j < 4; ++j) gr[j] = *(const f32x4*)(pg + j * 4);
        if (tid < 128) mr = mb[((size_t)bh * NL + qt * 64 + (tid >> 1)) * 32 + kt0 * 2 + (tid & 1)];
    }

    for (int kt = 0; kt < 8; ++kt) {
        __syncthreads();
        *(half8*)&k_lds[sr][sc] = kr0;  *(half8*)&k_lds[sr][sc + 8] = kr1;
        *(half8*)&vt_lds[sr][sc] = vr0; *(half8*)&vt_lds[sr][sc + 8] = vr1;
#pragma unroll
        for (int j = 0; j < 4; ++j) *(f32x4*)&bias_lds[sr][(tid & 3) * 16 + j * 4] = gr[j];
        if (tid < 128) mask_lds[tid >> 1][tid & 1] = mr;

        if (kt < 7) {
            const int ktg = kt0 + kt + 1;
            const _Float16* pk = &kb[((size_t)(bh * NL) + ktg * 64 + sr) * ND + sc];
            kr0 = *(const half8*)pk; kr1 = *(const half8*)(pk + 8);
            const _Float16* pv = &vtb[((size_t)(bh * ND) + sr) * NL + ktg * 64 + sc];
            vr0 = *(const half8*)pv; vr1 = *(const half8*)(pv + 8);
            const float* pg = &kern[((size_t)bh * NL + ktg * 64 + sr) * NL + qt * 64 + sc];
#pragma unroll
            for (int j = 0; j < 4; ++j) gr[j] = *(const f32x4*)(pg + j * 4);
            if (tid < 128) mr = mb[((size_t)bh * NL + qt * 64 + (tid >> 1)) * 32 + ktg * 2 + (tid & 1)];
        }
        __syncthreads();

        // S = (q*scale) @ k^T
        f32x4 S[4];
#pragma unroll
        for (int ns = 0; ns < 4; ++ns) {
            f32x4 a = {};
            half8 bk0 = *(const half8*)&k_lds[ns * 16 + c][quad * 8];
            half8 bk1 = *(const half8*)&k_lds[ns * 16 + c][32 + quad * 8];
            a = MFMA16(aq0, bk0, a);
            a = MFMA16(aq1, bk1, a);
            S[ns] = a;
        }

        unsigned mw0[4], mw1[4];
#pragma unroll
        for (int r = 0; r < 4; ++r) {
            const int row = wave * 16 + quad * 4 + r;
            uint2 mm = *(const uint2*)&mask_lds[row][0];
            mw0[r] = mm.x; mw1[r] = mm.y;
        }

        // + kernel^T (bias_lds is [k-in-tile][q-in-64tile]; wave offset REQUIRED)
#pragma unroll
        for (int ns = 0; ns < 4; ++ns) {
            f32x4 bv = *(const f32x4*)&bias_lds[ns * 16 + c][wave * 16 + quad * 4];
            const int bit = ((ns & 1) << 4) + c;
#pragma unroll
            for (int r = 0; r < 4; ++r) {
                unsigned w = (ns < 2) ? mw0[r] : mw1[r];
                bool mk = (w >> bit) & 1u;
                S[ns][r] = mk ? -1e30f : (S[ns][r] + bv[r]);
            }
        }

        // online softmax across this tile's 64 k-cols
        float pmax[4], al[4];
#pragma unroll
        for (int r = 0; r < 4; ++r) {
            float t = fmaxf(fmaxf(S[0][r], S[1][r]), fmaxf(S[2][r], S[3][r]));
            t = fmaxf(t, __shfl_xor(t, 1));
            t = fmaxf(t, __shfl_xor(t, 2));
            t = fmaxf(t, __shfl_xor(t, 4));
            t = fmaxf(t, __shfl_xor(t, 8));
            float mn = fmaxf(m_i[r], t);
            al[r] = __expf(m_i[r] - mn);
            m_i[r] = mn;
            pmax[r] = mn;
        }
        float rs[4] = {0.f, 0.f, 0.f, 0.f};
#pragma unroll
        for (int ns = 0; ns < 4; ++ns)
#pragma unroll
            for (int r = 0; r < 4; ++r) {
                float p = __expf(S[ns][r] - pmax[r]);
                S[ns][r] = p;
                rs[r] += p;
            }
#pragma unroll
        for (int r = 0; r < 4; ++r) {
            float t = rs[r];
            t += __shfl_xor(t, 1);
            t += __shfl_xor(t, 2);
            t += __shfl_xor(t, 4);
            t += __shfl_xor(t, 8);
            l_i[r] = l_i[r] * al[r] + t;
        }
#pragma unroll
        for (int ds = 0; ds < 4; ++ds)
#pragma unroll
            for (int r = 0; r < 4; ++r)
                O[ds][r] *= al[r];

        // P (C-layout) -> LDS -> A-layout; wave-local rows, lgkmcnt suffices.
#pragma unroll
        for (int ns = 0; ns < 4; ++ns)
#pragma unroll
            for (int r = 0; r < 4; ++r)
                p_lds[wave * 16 + quad * 4 + r][ns * 16 + c] = (_Float16)S[ns][r];
        __asm__ volatile("s_waitcnt lgkmcnt(0)" ::: "memory");

#pragma unroll
        for (int ks = 0; ks < 2; ++ks) {
            half8 ap = *(const half8*)&p_lds[wave * 16 + c][ks * 32 + quad * 8];
#pragma unroll
            for (int ds = 0; ds < 4; ++ds) {
                half8 bv = *(const half8*)&vt_lds[ds * 16 + c][ks * 32 + quad * 8];
                O[ds] = MFMA16(ap, bv, O[ds]);
            }
        }
    }

    // write unnormalized partial (f16) + per-row (m, l)
    const int ub = (bh * 16 + qt) * 2 + half;
    _Float16* pOb = pO + (size_t)ub * 4096;
#pragma unroll
    for (int ds = 0; ds < 4; ++ds)
#pragma unroll
        for (int r = 0; r < 4; ++r)
            pOb[(wave * 16 + quad * 4 + r) * 64 + ds * 16 + c] = (_Float16)O[ds][r];
    if (c == 0) {
#pragma unroll
        for (int r = 0; r < 4; ++r) {
            const int row = wave * 16 + quad * 4 + r;
            pm[(size_t)ub * 64 + row] = m_i[r];
            pl[(size_t)ub * 64 + row] = l_i[r];
        }
    }
}

// ---------------------------------------------------------------------------
// Output projection FUSED with split-K merge: A-tile staging merges the two
// f16 partials (scales from pm/pl) during the LDS store. 64-row mtile = one
// (b, qt); each 64-col k0 block = one head h -> u0 = ((b*8+h)*16+qt)*2.
// ---------------------------------------------------------------------------
__global__ __launch_bounds__(256) void out_gemm_kernel(
    const _Float16* __restrict__ pO, const float* __restrict__ pm, const float* __restrict__ pl,
    const float* __restrict__ w, const float* __restrict__ bias,
    float* __restrict__ out)
{
    const int mtile = blockIdx.x, ntile = blockIdx.y;
    const int bb = mtile >> 4, qt = mtile & 15;
    __shared__ __align__(16) _Float16 a_lds[64][72];
    __shared__ __align__(16) _Float16 b_lds[64][72];
    const int tid = threadIdx.x, wave = tid >> 6, lane = tid & 63, quad = lane >> 4, c = lane & 15;
    const int wm = wave >> 1, wn = wave & 1;
    f32x4 acc[2][2] = {};

    const int sr = tid >> 2, sc = (tid & 3) * 16;

    half8 p0a, p0b, p1a, p1b;
    f32x4 br[4];
    float m0, l0, m1, l1;

    auto fetch = [&](int k0) {
        const int h = k0 >> 6;
        const int u0 = ((bb * 8 + h) * 16 + qt) * 2;
        const _Float16* q0 = pO + (size_t)u0 * 4096 + sr * 64 + sc;
        p0a = *(const half8*)q0; p0b = *(const half8*)(q0 + 8);
        const _Float16* q1 = q0 + 4096;
        p1a = *(const half8*)q1; p1b = *(const half8*)(q1 + 8);
        m0 = pm[(size_t)u0 * 64 + sr]; l0 = pl[(size_t)u0 * 64 + sr];
        m1 = pm[(size_t)(u0 + 1) * 64 + sr]; l1 = pl[(size_t)(u0 + 1) * 64 + sr];
        const float* pb = &w[(size_t)(ntile * 64 + sr) * NHD + k0 + sc];
#pragma unroll
        for (int j = 0; j < 4; ++j) br[j] = *(const f32x4*)(pb + j * 4);
    };

    fetch(0);
    for (int k0 = 0; k0 < NHD; k0 += 64) {
        // merge scales (exact split-K softmax combine)
        const float mx = fmaxf(m0, m1);
        const float e0 = __expf(m0 - mx), e1 = __expf(m1 - mx);
        const float linv = 1.0f / (l0 * e0 + l1 * e1);
        const float s0 = e0 * linv, s1 = e1 * linv;
        half8 ah0, ah1, bh0, bh1;
#pragma unroll
        for (int j = 0; j < 8; ++j) {
            ah0[j] = (_Float16)((float)p0a[j] * s0 + (float)p1a[j] * s1);
            ah1[j] = (_Float16)((float)p0b[j] * s0 + (float)p1b[j] * s1);
        }
#pragma unroll
        for (int j = 0; j < 4; ++j) {
            bh0[j] = (_Float16)br[0][j]; bh0[4 + j] = (_Float16)br[1][j];
            bh1[j] = (_Float16)br[2][j]; bh1[4 + j] = (_Float16)br[3][j];
        }
        __syncthreads();
        *(half8*)&a_lds[sr][sc] = ah0; *(half8*)&a_lds[sr][sc + 8] = ah1;
        *(half8*)&b_lds[sr][sc] = bh0; *(half8*)&b_lds[sr][sc + 8] = bh1;
        if (k0 < NHD - 64) fetch(k0 + 64);
        __syncthreads();

#pragma unroll
        for (int kk = 0; kk < 2; ++kk) {
            half8 af0 = *(const half8*)&a_lds[wm * 32 + c][kk * 32 + quad * 8];
            half8 af1 = *(const half8*)&a_lds[wm * 32 + 16 + c][kk * 32 + quad * 8];
            half8 bf0 = *(const half8*)&b_lds[wn * 32 + c][kk * 32 + quad * 8];
            half8 bf1 = *(const half8*)&b_lds[wn * 32 + 16 + c][kk * 32 + quad * 8];
            acc[0][0] = MFMA16(af0, bf0, acc[0][0]);
            acc[0][1] = MFMA16(af0, bf1, acc[0][1]);
            acc[1][0] = MFMA16(af1, bf0, acc[1][0]);
            acc[1][1] = MFMA16(af1, bf1, acc[1][1]);
        }
    }

#pragma unroll
    for (int ms = 0; ms < 2; ++ms)
#pragma unroll
    for (int ns = 0; ns < 2; ++ns) {
        const int Cc = ntile * 64 + wn * 32 + ns * 16 + c;
        const float bv = bias[Cc];
#pragma unroll
        for (int r = 0; r < 4; ++r) {
            const int R = mtile * 64 + wm * 32 + ms * 16 + quad * 4 + r;
            out[(size_t)R * NHD + Cc] = acc[ms][ns][r] + bv;
        }
    }
}

extern "C" void kernel_launch(void* const* d_in, const int* in_sizes, int n_in,
                              void* d_out, int out_size, void* d_ws, size_t ws_size,
                              hipStream_t stream)
{
    const float* query = (const float*)d_in[0];
    const float* key_  = (const float*)d_in[1];
    const float* value = (const float*)d_in[2];
    const void*  mask  = d_in[3];
    const float* kern  = (const float*)d_in[5];
    const float* ipw   = (const float*)d_in[6];
    const float* ipb   = (const float*)d_in[7];
    const float* outw  = (const float*)d_in[8];
    const float* outb  = (const float*)d_in[9];

    char* ws = (char*)d_ws;
    _Float16* qb  = (_Float16*)(ws);                    // 4 MB  [BH][L][D]
    _Float16* kb  = (_Float16*)(ws + (4ull << 20));     // 4 MB  [BH][L][D]
    _Float16* vtb = (_Float16*)(ws + (8ull << 20));     // 4 MB  [BH][D][L]
    _Float16* pO  = (_Float16*)(ws + (16ull << 20));    // 8 MB  [1024][64][64] f16
    float* pm     = (float*)(ws + (32ull << 20));       // 256 KB
    float* pl     = (float*)(ws + (33ull << 20));       // 256 KB
    unsigned* mb  = (unsigned*)(ws + (40ull << 20));    // 4 MB

    bitmask_kernel<<<4096, 256, 0, stream>>>(mask, mb);
    qkv_gemm_kernel<<<dim3(32, 8, 3), 256, 0, stream>>>(query, key_, value, ipw, ipb, qb, kb, vtb);
    attn_kernel<<<dim3(16, 32, 2), 256, 0, stream>>>(qb, kb, vtb, kern, mb, pO, pm, pl);
    out_gemm_kernel<<<dim3(64, 8), 256, 0, stream>>>(pO, pm, pl, outw, outb, (float*)d_out);
}